// Round 1
// baseline (487.005 us; speedup 1.0000x reference)
//
#include <hip/hip_runtime.h>

#define NUM_SEG 40000
#define BN_EPS 1e-3f

// ---------------- detect int64 vs int32 layout of unq_inv ----------------
// If the buffer holds int64 (values < 40000), the high 32-bit words are all 0.
// Sample odd 32-bit words near the middle (stay < N words so we never read OOB
// for the int32 case). For int32 data these words are sorted values ~20000 != 0.
__global__ void k_detect(const unsigned int* __restrict__ u, int N, int* __restrict__ flag) {
    int w = ((N / 2) | 1) + 2 * (int)threadIdx.x;
    unsigned v = (w < N) ? u[w] : 0u;
    unsigned long long b = __ballot(v != 0u);
    if (threadIdx.x == 0) *flag = (b == 0ull) ? 1 : 0;
}

__global__ void k_convert(const void* __restrict__ u, int N, const int* __restrict__ flag,
                          int* __restrict__ out32) {
    int i = blockIdx.x * 256 + threadIdx.x;
    if (i >= N) return;
    if (*flag) out32[i] = (int)((const long long*)u)[i];
    else       out32[i] = ((const int*)u)[i];
}

// ---------------- k1: x = in @ W, raw x -> out[:, :64], per-block stats ----------------
// 128 threads, tile = 128 points x 64 ch. Thread: pg = tid&15 (points pg+16i),
// cg = tid>>4 (channels cg*4..+3 and 32+cg*4..+3). 8x8 register tile.
__global__ __launch_bounds__(128) void k1_matmul(
    const float* __restrict__ in, const float* __restrict__ W,
    float* __restrict__ out, float* __restrict__ sums, float* __restrict__ sqs,
    int N, int NB) {
    __shared__ float sIn[128][68];   // stride 68 floats = 272 B (16B aligned, breaks bank aliasing)
    __shared__ float sW[64][64];
    const int tid = threadIdx.x;
    const int blk = blockIdx.x;
    const long p0 = (long)blk * 128;

    #pragma unroll
    for (int it = 0; it < 8; ++it) {         // stage W (1024 float4)
        int f = it * 128 + tid;
        float4 w4 = ((const float4*)W)[f];
        int k = f >> 4, c0 = (f & 15) << 2;
        *(float4*)&sW[k][c0] = w4;
    }
    #pragma unroll
    for (int it = 0; it < 16; ++it) {        // stage input tile (2048 float4)
        int f = it * 128 + tid;
        int p = f >> 4, k0 = (f & 15) << 2;
        long gp = p0 + p;
        float4 v = make_float4(0.f, 0.f, 0.f, 0.f);
        if (gp < N) v = ((const float4*)in)[gp * 16 + (f & 15)];
        *(float4*)&sIn[p][k0] = v;
    }
    __syncthreads();

    const int pg = tid & 15;
    const int cg = tid >> 4;
    float acc[8][8] = {};
    for (int k0 = 0; k0 < 64; k0 += 4) {
        float4 a[8];
        #pragma unroll
        for (int i = 0; i < 8; ++i) a[i] = *(const float4*)&sIn[pg + 16 * i][k0];
        #pragma unroll
        for (int kk = 0; kk < 4; ++kk) {
            float4 wlo = *(const float4*)&sW[k0 + kk][cg << 2];
            float4 whi = *(const float4*)&sW[k0 + kk][32 + (cg << 2)];
            #pragma unroll
            for (int i = 0; i < 8; ++i) {
                float av = (&a[i].x)[kk];
                acc[i][0] = fmaf(av, wlo.x, acc[i][0]);
                acc[i][1] = fmaf(av, wlo.y, acc[i][1]);
                acc[i][2] = fmaf(av, wlo.z, acc[i][2]);
                acc[i][3] = fmaf(av, wlo.w, acc[i][3]);
                acc[i][4] = fmaf(av, whi.x, acc[i][4]);
                acc[i][5] = fmaf(av, whi.y, acc[i][5]);
                acc[i][6] = fmaf(av, whi.z, acc[i][6]);
                acc[i][7] = fmaf(av, whi.w, acc[i][7]);
            }
        }
    }
    // raw x -> left half of out (normalized later by k3)
    #pragma unroll
    for (int i = 0; i < 8; ++i) {
        long p = p0 + pg + 16 * i;
        if (p < N) {
            ((float4*)out)[p * 32 + cg]     = make_float4(acc[i][0], acc[i][1], acc[i][2], acc[i][3]);
            ((float4*)out)[p * 32 + 8 + cg] = make_float4(acc[i][4], acc[i][5], acc[i][6], acc[i][7]);
        }
    }
    // per-channel partial sums over this block's points (tail rows are 0 -> harmless)
    float s[8], q[8];
    #pragma unroll
    for (int j = 0; j < 8; ++j) {
        s[j] = 0.f; q[j] = 0.f;
        #pragma unroll
        for (int i = 0; i < 8; ++i) { s[j] += acc[i][j]; q[j] += acc[i][j] * acc[i][j]; }
    }
    #pragma unroll
    for (int off = 1; off < 16; off <<= 1) {
        #pragma unroll
        for (int j = 0; j < 8; ++j) {
            s[j] += __shfl_xor(s[j], off);
            q[j] += __shfl_xor(q[j], off);
        }
    }
    if (pg == 0) {
        #pragma unroll
        for (int j = 0; j < 8; ++j) {
            int c = (j < 4) ? ((cg << 2) + j) : (32 + (cg << 2) + (j - 4));
            sums[(long)c * NB + blk] = s[j];
            sqs [(long)c * NB + blk] = q[j];
        }
    }
}

// ---------------- k2: reduce partials -> scale/shift per channel ----------------
__global__ __launch_bounds__(256) void k2_stats(
    const float* __restrict__ sums, const float* __restrict__ sqs,
    const float* __restrict__ gamma, const float* __restrict__ beta,
    float* __restrict__ ss, int N, int NB) {
    int c = blockIdx.x;
    int tid = threadIdx.x;
    float s = 0.f, q = 0.f;
    for (int i = tid; i < NB; i += 256) { s += sums[(long)c * NB + i]; q += sqs[(long)c * NB + i]; }
    __shared__ float ls[256], lq[256];
    ls[tid] = s; lq[tid] = q;
    __syncthreads();
    for (int off = 128; off > 0; off >>= 1) {
        if (tid < off) { ls[tid] += ls[tid + off]; lq[tid] += lq[tid + off]; }
        __syncthreads();
    }
    if (tid == 0) {
        float mean = ls[0] / (float)N;
        float var  = lq[0] / (float)N - mean * mean;   // biased, matches jnp.var
        float sc = gamma[c] * rsqrtf(var + BN_EPS);
        float sh = beta[c] - mean * sc;
        ss[c] = sc; ss[64 + c] = sh;
    }
}

// ---------------- k3: normalize+ReLU in place, run-compressed segment max ----------------
// block = 4 waves; each wave scans 64 contiguous points, lane = channel.
__global__ __launch_bounds__(256) void k3_bnrelu_segmax(
    float* __restrict__ out, const int* __restrict__ unq,
    const float* __restrict__ ss, unsigned int* __restrict__ segmax, int N) {
    const int tid = threadIdx.x;
    const int lane = tid & 63;
    const int wave = tid >> 6;
    const long base = (long)blockIdx.x * 256 + (long)wave * 64;
    if (base >= N) return;
    const float sc = ss[lane];
    const float sh = ss[64 + lane];
    const long pend = min(base + 64, (long)N);

    int cur = unq[base];
    float runmax = 0.f;
    float x_next = out[base * 128 + lane];
    int seg_next = cur;
    for (long p = base; p < pend; ++p) {
        float x = x_next;
        int seg = seg_next;
        if (p + 1 < pend) {                      // prefetch (keeps loads ahead of stores/atomics)
            x_next = out[(p + 1) * 128 + lane];
            seg_next = unq[p + 1];
        }
        if (seg != cur) {
            atomicMax(&segmax[(long)cur * 64 + lane], __float_as_uint(runmax));
            cur = seg; runmax = 0.f;
        }
        float y = fmaxf(fmaf(x, sc, sh), 0.f);
        out[p * 128 + lane] = y;
        runmax = fmaxf(runmax, y);               // y>=0 so uint-ordered atomicMax is exact
    }
    atomicMax(&segmax[(long)cur * 64 + lane], __float_as_uint(runmax));
}

// ---------------- k4: gather voxel max -> out[:, 64:128] ----------------
__global__ __launch_bounds__(256) void k4_gather(
    float* __restrict__ out, const int* __restrict__ unq,
    const float* __restrict__ segmax_f, int N) {
    long t = (long)blockIdx.x * 256 + threadIdx.x;
    long p = t >> 4;
    int qq = (int)(t & 15);
    if (p >= N) return;
    int seg = unq[p];
    float4 v = ((const float4*)segmax_f)[(long)seg * 16 + qq];
    ((float4*)out)[p * 32 + 16 + qq] = v;
}

extern "C" void kernel_launch(void* const* d_in, const int* in_sizes, int n_in,
                              void* d_out, int out_size, void* d_ws, size_t ws_size,
                              hipStream_t stream) {
    const float* in    = (const float*)d_in[0];
    const float* W     = (const float*)d_in[1];
    const float* gamma = (const float*)d_in[2];
    const float* beta  = (const float*)d_in[3];
    const void*  unq   = d_in[4];
    float* out = (float*)d_out;

    const int N  = in_sizes[0] / 64;
    const int NB = (N + 127) / 128;

    char* ws = (char*)d_ws;
    unsigned int* segmax = (unsigned int*)ws;                    // 40000*64*4 = 10.24 MB
    size_t off = (size_t)NUM_SEG * 64 * 4;
    float* sums = (float*)(ws + off); off += (size_t)64 * NB * 4;
    float* sqs  = (float*)(ws + off); off += (size_t)64 * NB * 4;
    float* ss   = (float*)(ws + off); off += 512;
    int*   flag = (int*)(ws + off);   off += 16;
    int*   unq32= (int*)(ws + off);   off += (size_t)N * 4;      // total ~18.3 MB

    hipMemsetAsync(segmax, 0, (size_t)NUM_SEG * 64 * 4, stream);
    k_detect<<<1, 64, 0, stream>>>((const unsigned int*)unq, N, flag);
    k_convert<<<(N + 255) / 256, 256, 0, stream>>>(unq, N, flag, unq32);
    k1_matmul<<<NB, 128, 0, stream>>>(in, W, out, sums, sqs, N, NB);
    k2_stats<<<64, 256, 0, stream>>>(sums, sqs, gamma, beta, ss, N, NB);
    k3_bnrelu_segmax<<<(N + 255) / 256, 256, 0, stream>>>(out, unq32, ss, segmax, N);
    k4_gather<<<(int)(((long)N * 16 + 255) / 256), 256, 0, stream>>>(out, unq32, (const float*)segmax, N);
}

// Round 2
// 486.438 us; speedup vs baseline: 1.0012x; 1.0012x over previous
//
#include <hip/hip_runtime.h>

#define NUM_SEG 40000
#define BN_EPS 1e-3f

// ---------------- zero-fill segmax (hipMemsetAsync's fill kernel ran 302us; this runs ~3us) ----------------
__global__ __launch_bounds__(256) void k_zero(float4* __restrict__ p, int n4) {
    int i = blockIdx.x * 256 + threadIdx.x;
    if (i < n4) p[i] = make_float4(0.f, 0.f, 0.f, 0.f);
}

// ---------------- detect int64 vs int32 layout of unq_inv ----------------
// If the buffer holds int64 (values < 40000), the high 32-bit words are all 0.
// Sample odd 32-bit words near the middle (stay < N words so we never read OOB
// for the int32 case). For int32 data these words are sorted values ~20000 != 0.
__global__ void k_detect(const unsigned int* __restrict__ u, int N, int* __restrict__ flag) {
    int w = ((N / 2) | 1) + 2 * (int)threadIdx.x;
    unsigned v = (w < N) ? u[w] : 0u;
    unsigned long long b = __ballot(v != 0u);
    if (threadIdx.x == 0) *flag = (b == 0ull) ? 1 : 0;
}

__global__ void k_convert(const void* __restrict__ u, int N, const int* __restrict__ flag,
                          int* __restrict__ out32) {
    int i = blockIdx.x * 256 + threadIdx.x;
    if (i >= N) return;
    if (*flag) out32[i] = (int)((const long long*)u)[i];
    else       out32[i] = ((const int*)u)[i];
}

// ---------------- k1: x = in @ W, raw x -> out[:, :64], per-block stats ----------------
// 128 threads, tile = 128 points x 64 ch. Thread: pg = tid&15 (points pg+16i),
// cg = tid>>4 (channels cg*4..+3 and 32+cg*4..+3). 8x8 register tile.
__global__ __launch_bounds__(128) void k1_matmul(
    const float* __restrict__ in, const float* __restrict__ W,
    float* __restrict__ out, float* __restrict__ sums, float* __restrict__ sqs,
    int N, int NB) {
    __shared__ float sIn[128][68];   // stride 68 floats = 272 B (16B aligned, breaks bank aliasing)
    __shared__ float sW[64][64];
    const int tid = threadIdx.x;
    const int blk = blockIdx.x;
    const long p0 = (long)blk * 128;

    #pragma unroll
    for (int it = 0; it < 8; ++it) {         // stage W (1024 float4)
        int f = it * 128 + tid;
        float4 w4 = ((const float4*)W)[f];
        int k = f >> 4, c0 = (f & 15) << 2;
        *(float4*)&sW[k][c0] = w4;
    }
    #pragma unroll
    for (int it = 0; it < 16; ++it) {        // stage input tile (2048 float4)
        int f = it * 128 + tid;
        int p = f >> 4, k0 = (f & 15) << 2;
        long gp = p0 + p;
        float4 v = make_float4(0.f, 0.f, 0.f, 0.f);
        if (gp < N) v = ((const float4*)in)[gp * 16 + (f & 15)];
        *(float4*)&sIn[p][k0] = v;
    }
    __syncthreads();

    const int pg = tid & 15;
    const int cg = tid >> 4;
    float acc[8][8] = {};
    for (int k0 = 0; k0 < 64; k0 += 4) {
        float4 a[8];
        #pragma unroll
        for (int i = 0; i < 8; ++i) a[i] = *(const float4*)&sIn[pg + 16 * i][k0];
        #pragma unroll
        for (int kk = 0; kk < 4; ++kk) {
            float4 wlo = *(const float4*)&sW[k0 + kk][cg << 2];
            float4 whi = *(const float4*)&sW[k0 + kk][32 + (cg << 2)];
            #pragma unroll
            for (int i = 0; i < 8; ++i) {
                float av = (&a[i].x)[kk];
                acc[i][0] = fmaf(av, wlo.x, acc[i][0]);
                acc[i][1] = fmaf(av, wlo.y, acc[i][1]);
                acc[i][2] = fmaf(av, wlo.z, acc[i][2]);
                acc[i][3] = fmaf(av, wlo.w, acc[i][3]);
                acc[i][4] = fmaf(av, whi.x, acc[i][4]);
                acc[i][5] = fmaf(av, whi.y, acc[i][5]);
                acc[i][6] = fmaf(av, whi.z, acc[i][6]);
                acc[i][7] = fmaf(av, whi.w, acc[i][7]);
            }
        }
    }
    // raw x -> left half of out (normalized later by k3)
    #pragma unroll
    for (int i = 0; i < 8; ++i) {
        long p = p0 + pg + 16 * i;
        if (p < N) {
            ((float4*)out)[p * 32 + cg]     = make_float4(acc[i][0], acc[i][1], acc[i][2], acc[i][3]);
            ((float4*)out)[p * 32 + 8 + cg] = make_float4(acc[i][4], acc[i][5], acc[i][6], acc[i][7]);
        }
    }
    // per-channel partial sums over this block's points (tail rows are 0 -> harmless)
    float s[8], q[8];
    #pragma unroll
    for (int j = 0; j < 8; ++j) {
        s[j] = 0.f; q[j] = 0.f;
        #pragma unroll
        for (int i = 0; i < 8; ++i) { s[j] += acc[i][j]; q[j] += acc[i][j] * acc[i][j]; }
    }
    #pragma unroll
    for (int off = 1; off < 16; off <<= 1) {
        #pragma unroll
        for (int j = 0; j < 8; ++j) {
            s[j] += __shfl_xor(s[j], off);
            q[j] += __shfl_xor(q[j], off);
        }
    }
    if (pg == 0) {
        #pragma unroll
        for (int j = 0; j < 8; ++j) {
            int c = (j < 4) ? ((cg << 2) + j) : (32 + (cg << 2) + (j - 4));
            sums[(long)c * NB + blk] = s[j];
            sqs [(long)c * NB + blk] = q[j];
        }
    }
}

// ---------------- k2: reduce partials -> scale/shift per channel ----------------
__global__ __launch_bounds__(256) void k2_stats(
    const float* __restrict__ sums, const float* __restrict__ sqs,
    const float* __restrict__ gamma, const float* __restrict__ beta,
    float* __restrict__ ss, int N, int NB) {
    int c = blockIdx.x;
    int tid = threadIdx.x;
    float s = 0.f, q = 0.f;
    for (int i = tid; i < NB; i += 256) { s += sums[(long)c * NB + i]; q += sqs[(long)c * NB + i]; }
    __shared__ float ls[256], lq[256];
    ls[tid] = s; lq[tid] = q;
    __syncthreads();
    for (int off = 128; off > 0; off >>= 1) {
        if (tid < off) { ls[tid] += ls[tid + off]; lq[tid] += lq[tid + off]; }
        __syncthreads();
    }
    if (tid == 0) {
        float mean = ls[0] / (float)N;
        float var  = lq[0] / (float)N - mean * mean;   // biased, matches jnp.var
        float sc = gamma[c] * rsqrtf(var + BN_EPS);
        float sh = beta[c] - mean * sc;
        ss[c] = sc; ss[64 + c] = sh;
    }
}

// ---------------- k3: normalize+ReLU in place, run-compressed segment max ----------------
// block = 4 waves; each wave scans 64 contiguous points, lane = channel.
__global__ __launch_bounds__(256) void k3_bnrelu_segmax(
    float* __restrict__ out, const int* __restrict__ unq,
    const float* __restrict__ ss, unsigned int* __restrict__ segmax, int N) {
    const int tid = threadIdx.x;
    const int lane = tid & 63;
    const int wave = tid >> 6;
    const long base = (long)blockIdx.x * 256 + (long)wave * 64;
    if (base >= N) return;
    const float sc = ss[lane];
    const float sh = ss[64 + lane];
    const long pend = min(base + 64, (long)N);

    int cur = unq[base];
    float runmax = 0.f;
    float x_next = out[base * 128 + lane];
    int seg_next = cur;
    for (long p = base; p < pend; ++p) {
        float x = x_next;
        int seg = seg_next;
        if (p + 1 < pend) {                      // prefetch (keeps loads ahead of stores/atomics)
            x_next = out[(p + 1) * 128 + lane];
            seg_next = unq[p + 1];
        }
        if (seg != cur) {
            atomicMax(&segmax[(long)cur * 64 + lane], __float_as_uint(runmax));
            cur = seg; runmax = 0.f;
        }
        float y = fmaxf(fmaf(x, sc, sh), 0.f);
        out[p * 128 + lane] = y;
        runmax = fmaxf(runmax, y);               // y>=0 so uint-ordered atomicMax is exact
    }
    atomicMax(&segmax[(long)cur * 64 + lane], __float_as_uint(runmax));
}

// ---------------- k4: gather voxel max -> out[:, 64:128] ----------------
__global__ __launch_bounds__(256) void k4_gather(
    float* __restrict__ out, const int* __restrict__ unq,
    const float* __restrict__ segmax_f, int N) {
    long t = (long)blockIdx.x * 256 + threadIdx.x;
    long p = t >> 4;
    int qq = (int)(t & 15);
    if (p >= N) return;
    int seg = unq[p];
    float4 v = ((const float4*)segmax_f)[(long)seg * 16 + qq];
    ((float4*)out)[p * 32 + 16 + qq] = v;
}

extern "C" void kernel_launch(void* const* d_in, const int* in_sizes, int n_in,
                              void* d_out, int out_size, void* d_ws, size_t ws_size,
                              hipStream_t stream) {
    const float* in    = (const float*)d_in[0];
    const float* W     = (const float*)d_in[1];
    const float* gamma = (const float*)d_in[2];
    const float* beta  = (const float*)d_in[3];
    const void*  unq   = d_in[4];
    float* out = (float*)d_out;

    const int N  = in_sizes[0] / 64;
    const int NB = (N + 127) / 128;

    char* ws = (char*)d_ws;
    unsigned int* segmax = (unsigned int*)ws;                    // 40000*64*4 = 10.24 MB
    size_t off = (size_t)NUM_SEG * 64 * 4;
    float* sums = (float*)(ws + off); off += (size_t)64 * NB * 4;
    float* sqs  = (float*)(ws + off); off += (size_t)64 * NB * 4;
    float* ss   = (float*)(ws + off); off += 512;
    int*   flag = (int*)(ws + off);   off += 16;
    int*   unq32= (int*)(ws + off);   off += (size_t)N * 4;      // total ~18.3 MB

    const int n4 = NUM_SEG * 64 / 4;                             // 640k float4 = 10.24 MB
    k_zero<<<(n4 + 255) / 256, 256, 0, stream>>>((float4*)segmax, n4);
    k_detect<<<1, 64, 0, stream>>>((const unsigned int*)unq, N, flag);
    k_convert<<<(N + 255) / 256, 256, 0, stream>>>(unq, N, flag, unq32);
    k1_matmul<<<NB, 128, 0, stream>>>(in, W, out, sums, sqs, N, NB);
    k2_stats<<<64, 256, 0, stream>>>(sums, sqs, gamma, beta, ss, N, NB);
    k3_bnrelu_segmax<<<(N + 255) / 256, 256, 0, stream>>>(out, unq32, ss, segmax, N);
    k4_gather<<<(int)(((long)N * 16 + 255) / 256), 256, 0, stream>>>(out, unq32, (const float*)segmax, N);
}